// Round 4
// baseline (36.285 us; speedup 1.0000x reference)
//
#include <hip/hip_runtime.h>
#include <cstddef>

namespace {

constexpr int B     = 512;
constexpr int C     = 2047;   // 2^(DEPTH+1) - 1
constexpr int L     = 4;
constexpr int DEPTH = 10;
constexpr int BLOCK = 256;

__device__ __forceinline__ float lse4(float v0, float v1, float v2, float v3) {
    const float m = fmaxf(fmaxf(v0, v1), fmaxf(v2, v3));
    const float s = __expf(v0 - m) + __expf(v1 - m) + __expf(v2 - m) + __expf(v3 - m);
    return m + __logf(s);
}

// One block per batch element. alphas/betas for the whole tree live in LDS
// (2 * 2047 * 4 floats = 65,504 B -> 2 blocks/CU). Upward sweep iterates over
// PARENTS (each thread owns one parent and folds in both children) so the
// duplicate-parent accumulation is race-free without atomics.
__global__ __launch_bounds__(BLOCK) void treecrf_kernel(
    const float* __restrict__ X,      // (B, C, L)
    const float* __restrict__ pairs,  // (C, C, L, L)
    float* __restrict__ out)          // (B, C, L) = log_softmax(X+alphas+betas)
{
    __shared__ float alphas[C * L];
    __shared__ float betas[C * L];

    const int b   = blockIdx.x;
    const int tid = threadIdx.x;
    const float* __restrict__ Xb = X + (size_t)b * (C * L);
    float* __restrict__ Ob       = out + (size_t)b * (C * L);

    for (int i = tid; i < C * L; i += BLOCK) {
        alphas[i] = 0.0f;
        betas[i]  = 0.0f;
    }
    __syncthreads();

    // ---- upward: leaves -> root. Level d supplies messages to parents at d-1.
    for (int d = DEPTH; d >= 1; --d) {
        const int pbase = (1 << (d - 1)) - 1;   // first parent index at depth d-1
        const int pn    = 1 << (d - 1);         // number of parents
        for (int pi = tid; pi < pn; pi += BLOCK) {
            const int p = pbase + pi;
            float acc0 = 0.f, acc1 = 0.f, acc2 = 0.f, acc3 = 0.f;
            #pragma unroll
            for (int ci = 0; ci < 2; ++ci) {
                const int c = 2 * p + 1 + ci;
                const float4 x4 = *reinterpret_cast<const float4*>(Xb + c * L);
                const float4 a4 = *reinterpret_cast<const float4*>(&alphas[c * L]);
                const float l0 = x4.x + a4.x;
                const float l1 = x4.y + a4.y;
                const float l2 = x4.z + a4.z;
                const float l3 = x4.w + a4.w;
                // trans = pairs[p, c] : (L_i, L_j), 16 contiguous floats
                const float* __restrict__ t = pairs + ((size_t)p * C + c) * (L * L);
                const float4 t0 = *reinterpret_cast<const float4*>(t + 0);
                const float4 t1 = *reinterpret_cast<const float4*>(t + 4);
                const float4 t2 = *reinterpret_cast<const float4*>(t + 8);
                const float4 t3 = *reinterpret_cast<const float4*>(t + 12);
                acc0 += lse4(t0.x + l0, t0.y + l1, t0.z + l2, t0.w + l3);
                acc1 += lse4(t1.x + l0, t1.y + l1, t1.z + l2, t1.w + l3);
                acc2 += lse4(t2.x + l0, t2.y + l1, t2.z + l2, t2.w + l3);
                acc3 += lse4(t3.x + l0, t3.y + l1, t3.z + l2, t3.w + l3);
            }
            float4 up;
            const float4 prev = *reinterpret_cast<const float4*>(&alphas[p * L]);
            up.x = prev.x + acc0;
            up.y = prev.y + acc1;
            up.z = prev.z + acc2;
            up.w = prev.w + acc3;
            *reinterpret_cast<float4*>(&alphas[p * L]) = up;
        }
        __syncthreads();
    }

    // ---- downward: root -> leaves. Each child pulls from its parent.
    for (int d = 1; d <= DEPTH; ++d) {
        const int base = (1 << d) - 1;
        const int n    = 1 << d;
        for (int idx = tid; idx < n; idx += BLOCK) {
            const int c = base + idx;
            const int p = (c - 1) >> 1;
            const float4 x4 = *reinterpret_cast<const float4*>(Xb + p * L);
            const float4 b4 = *reinterpret_cast<const float4*>(&betas[p * L]);
            const float l0 = x4.x + b4.x;
            const float l1 = x4.y + b4.y;
            const float l2 = x4.z + b4.z;
            const float l3 = x4.w + b4.w;
            // trans = pairs[c, p] : (L_i, L_j)  (child-first index)
            const float* __restrict__ t = pairs + ((size_t)c * C + p) * (L * L);
            const float4 t0 = *reinterpret_cast<const float4*>(t + 0);
            const float4 t1 = *reinterpret_cast<const float4*>(t + 4);
            const float4 t2 = *reinterpret_cast<const float4*>(t + 8);
            const float4 t3 = *reinterpret_cast<const float4*>(t + 12);
            float4 m;
            m.x = lse4(t0.x + l0, t0.y + l1, t0.z + l2, t0.w + l3);
            m.y = lse4(t1.x + l0, t1.y + l1, t1.z + l2, t1.w + l3);
            m.z = lse4(t2.x + l0, t2.y + l1, t2.z + l2, t2.w + l3);
            m.w = lse4(t3.x + l0, t3.y + l1, t3.z + l2, t3.w + l3);
            *reinterpret_cast<float4*>(&betas[c * L]) = m;  // betas start at 0 -> set
        }
        __syncthreads();
    }

    // ---- output: log_softmax(X + alphas + betas) over labels
    for (int i = tid; i < C; i += BLOCK) {
        const float4 x4 = *reinterpret_cast<const float4*>(Xb + i * L);
        const float4 a4 = *reinterpret_cast<const float4*>(&alphas[i * L]);
        const float4 b4 = *reinterpret_cast<const float4*>(&betas[i * L]);
        const float g0 = x4.x + a4.x + b4.x;
        const float g1 = x4.y + a4.y + b4.y;
        const float g2 = x4.z + a4.z + b4.z;
        const float g3 = x4.w + a4.w + b4.w;
        const float z = lse4(g0, g1, g2, g3);
        float4 o;
        o.x = g0 - z;
        o.y = g1 - z;
        o.z = g2 - z;
        o.w = g3 - z;
        *reinterpret_cast<float4*>(Ob + i * L) = o;
    }
}

}  // namespace

extern "C" void kernel_launch(void* const* d_in, const int* in_sizes, int n_in,
                              void* d_out, int out_size, void* d_ws, size_t ws_size,
                              hipStream_t stream) {
    (void)in_sizes; (void)n_in; (void)out_size; (void)d_ws; (void)ws_size;
    const float* X     = (const float*)d_in[0];
    const float* pairs = (const float*)d_in[1];
    float* out         = (float*)d_out;
    treecrf_kernel<<<B, BLOCK, 0, stream>>>(X, pairs, out);
}

// Round 5
// 36.092 us; speedup vs baseline: 1.0053x; 1.0053x over previous
//
#include <hip/hip_runtime.h>
#include <cstddef>

namespace {

constexpr int B     = 512;
constexpr int C     = 2047;   // 2^(DEPTH+1) - 1
constexpr int L     = 4;
constexpr int DEPTH = 10;
constexpr int BLOCK = 512;
constexpr int NINT  = 1023;   // internal nodes (leaves' alphas are identically 0)

__device__ __forceinline__ float4 ld4(const float* p) {
    return *reinterpret_cast<const float4*>(p);
}
__device__ __forceinline__ void st4(float* p, float x, float y, float z, float w) {
    float4 v; v.x = x; v.y = y; v.z = z; v.w = w;
    *reinterpret_cast<float4*>(p) = v;
}

__device__ __forceinline__ float lse4(float v0, float v1, float v2, float v3) {
    const float m = fmaxf(fmaxf(v0, v1), fmaxf(v2, v3));
    const float s = __expf(v0 - m) + __expf(v1 - m) + __expf(v2 - m) + __expf(v3 - m);
    return m + __logf(s);
}

// message vector over parent labels: msg[i] = lse_j(t[i][j] + l[j]); t is 16
// contiguous floats (one 64B line of `pairs`).
__device__ __forceinline__ float4 msg4(const float* __restrict__ t,
                                       float l0, float l1, float l2, float l3) {
    const float4 t0 = ld4(t + 0);
    const float4 t1 = ld4(t + 4);
    const float4 t2 = ld4(t + 8);
    const float4 t3 = ld4(t + 12);
    float4 r;
    r.x = lse4(t0.x + l0, t0.y + l1, t0.z + l2, t0.w + l3);
    r.y = lse4(t1.x + l0, t1.y + l1, t1.z + l2, t1.w + l3);
    r.z = lse4(t2.x + l0, t2.y + l1, t2.z + l2, t2.w + l3);
    r.w = lse4(t3.x + l0, t3.y + l1, t3.z + l2, t3.w + l3);
    return r;
}

__device__ __forceinline__ void write_lsm(float* __restrict__ o,
                                          float g0, float g1, float g2, float g3) {
    const float z = lse4(g0, g1, g2, g3);
    st4(o, g0 - z, g1 - z, g2 - z, g3 - z);
}

// One block per batch element. alphas for internal nodes live in LDS; betas
// exist only as a double-buffered per-level frontier. Output (log_softmax of
// X+alpha+beta) is fused into the downward sweep. No LDS initialization is
// needed: every LDS slot is written exactly once before it is read.
__global__ __launch_bounds__(BLOCK, 4) void treecrf_kernel(
    const float* __restrict__ X,      // (B, C, L)
    const float* __restrict__ pairs,  // (C, C, L, L)
    float* __restrict__ out)          // (B, C, L)
{
    __shared__ float alphas[NINT * L];  // 16368 B, indexed by node id
    __shared__ float fbo[512 * L];      // betas frontier, odd depths  (max 512 @ d=9)
    __shared__ float fbe[256 * L];      // betas frontier, even depths (max 256 @ d=8)

    const int b   = blockIdx.x;
    const int tid = threadIdx.x;
    const float* __restrict__ Xb = X + (size_t)b * (C * L);
    float* __restrict__ Ob       = out + (size_t)b * (C * L);

    // ---- upward, level 10 -> 9: children are leaves (alpha = 0), one parent
    // per thread (512 parents at depth 9: nodes [511, 1023)).
    {
        const int p  = 511 + tid;
        const int c0 = 2 * p + 1;
        const float4 x0 = ld4(Xb + c0 * L);
        const float4 x1 = ld4(Xb + (c0 + 1) * L);
        const float4 m0 = msg4(pairs + ((size_t)p * C + c0) * 16,
                               x0.x, x0.y, x0.z, x0.w);
        const float4 m1 = msg4(pairs + ((size_t)p * C + c0 + 1) * 16,
                               x1.x, x1.y, x1.z, x1.w);
        st4(&alphas[p * L], m0.x + m1.x, m0.y + m1.y, m0.z + m1.z, m0.w + m1.w);
    }
    __syncthreads();

    // ---- upward, levels 9..1: internal children, alpha read from LDS.
    for (int d = 9; d >= 1; --d) {
        const int pn    = 1 << (d - 1);
        const int pbase = pn - 1;
        if (tid < pn) {
            const int p  = pbase + tid;
            const int c0 = 2 * p + 1;
            const float4 x0 = ld4(Xb + c0 * L);
            const float4 a0 = ld4(&alphas[c0 * L]);
            const float4 x1 = ld4(Xb + (c0 + 1) * L);
            const float4 a1 = ld4(&alphas[(c0 + 1) * L]);
            const float4 m0 = msg4(pairs + ((size_t)p * C + c0) * 16,
                                   x0.x + a0.x, x0.y + a0.y, x0.z + a0.z, x0.w + a0.w);
            const float4 m1 = msg4(pairs + ((size_t)p * C + c0 + 1) * 16,
                                   x1.x + a1.x, x1.y + a1.y, x1.z + a1.z, x1.w + a1.w);
            st4(&alphas[p * L], m0.x + m1.x, m0.y + m1.y, m0.z + m1.z, m0.w + m1.w);
        }
        __syncthreads();
    }

    // ---- downward level 1 (+ root output). beta(root) = 0.
    if (tid < 2) {
        const int c = 1 + tid;
        const float4 x0 = ld4(Xb);  // X[root]
        const float4 m  = msg4(pairs + (size_t)c * C * 16,  // pairs[c, 0]
                               x0.x, x0.y, x0.z, x0.w);
        st4(&fbo[(c - 1) * L], m.x, m.y, m.z, m.w);
        const float4 xc = ld4(Xb + c * L);
        const float4 ac = ld4(&alphas[c * L]);
        write_lsm(Ob + c * L, xc.x + ac.x + m.x, xc.y + ac.y + m.y,
                              xc.z + ac.z + m.z, xc.w + ac.w + m.w);
    } else if (tid == 2) {
        const float4 x0 = ld4(Xb);
        const float4 a0 = ld4(&alphas[0]);
        write_lsm(Ob, x0.x + a0.x, x0.y + a0.y, x0.z + a0.z, x0.w + a0.w);
    }
    __syncthreads();

    // ---- downward, levels 2..10, output fused.
    for (int d = 2; d <= DEPTH; ++d) {
        const int n     = 1 << d;
        const int base  = n - 1;
        const int pbase = (1 << (d - 1)) - 1;
        float* __restrict__ pbuf = ((d - 1) & 1) ? fbo : fbe;
        float* __restrict__ cbuf = (d & 1) ? fbo : fbe;
        for (int idx = tid; idx < n; idx += BLOCK) {
            const int c = base + idx;
            const int p = (c - 1) >> 1;
            const float4 xp = ld4(Xb + p * L);
            const float4 bp = ld4(&pbuf[(p - pbase) * L]);
            const float4 m  = msg4(pairs + ((size_t)c * C + p) * 16,  // pairs[c, p]
                                   xp.x + bp.x, xp.y + bp.y, xp.z + bp.z, xp.w + bp.w);
            if (d < DEPTH) st4(&cbuf[idx * L], m.x, m.y, m.z, m.w);
            const float4 xc = ld4(Xb + c * L);
            float a0 = 0.f, a1 = 0.f, a2 = 0.f, a3 = 0.f;
            if (d <= 9) {  // internal node: alpha from LDS; leaves have alpha = 0
                const float4 ac = ld4(&alphas[c * L]);
                a0 = ac.x; a1 = ac.y; a2 = ac.z; a3 = ac.w;
            }
            write_lsm(Ob + c * L, xc.x + a0 + m.x, xc.y + a1 + m.y,
                                  xc.z + a2 + m.z, xc.w + a3 + m.w);
        }
        if (d < DEPTH) __syncthreads();
    }
}

}  // namespace

extern "C" void kernel_launch(void* const* d_in, const int* in_sizes, int n_in,
                              void* d_out, int out_size, void* d_ws, size_t ws_size,
                              hipStream_t stream) {
    (void)in_sizes; (void)n_in; (void)out_size; (void)d_ws; (void)ws_size;
    const float* X     = (const float*)d_in[0];
    const float* pairs = (const float*)d_in[1];
    float* out         = (float*)d_out;
    treecrf_kernel<<<B, BLOCK, 0, stream>>>(X, pairs, out);
}